// Round 2
// baseline (79.283 us; speedup 1.0000x reference)
//
#include <hip/hip_runtime.h>
#include <cmath>

// JPEG layer, fully fused. Quantization-sensitive path (RGB->YCC, chroma
// mean, DCT, divide, round) runs in f64 so round() decisions match the
// numpy f64 reference exactly; post-round IDCT + color run in f32.

#define LEVELD 0.5019607843137255   // 128/255 (f64)
#define LEVELF 0.5019607843137255f

// Orthonormal 8x8 DCT-II matrix (row-major), f64-exact.
__device__ __constant__ double DMATD[64] = {
  0.3535533905932738,  0.3535533905932738,  0.3535533905932738,  0.3535533905932738,
  0.3535533905932738,  0.3535533905932738,  0.3535533905932738,  0.3535533905932738,

  0.4903926402016152,  0.4157348061512726,  0.2777851165098011,  0.0975451610080641,
 -0.0975451610080641, -0.2777851165098011, -0.4157348061512726, -0.4903926402016152,

  0.4619397662556434,  0.1913417161825449, -0.1913417161825449, -0.4619397662556434,
 -0.4619397662556434, -0.1913417161825449,  0.1913417161825449,  0.4619397662556434,

  0.4157348061512726, -0.0975451610080641, -0.4903926402016152, -0.2777851165098011,
  0.2777851165098011,  0.4903926402016152,  0.0975451610080641, -0.4157348061512726,

  0.3535533905932738, -0.3535533905932738, -0.3535533905932738,  0.3535533905932738,
  0.3535533905932738, -0.3535533905932738, -0.3535533905932738,  0.3535533905932738,

  0.2777851165098011, -0.4903926402016152,  0.0975451610080641,  0.4157348061512726,
 -0.4157348061512726, -0.0975451610080641,  0.4903926402016152, -0.2777851165098011,

  0.1913417161825449, -0.4619397662556434,  0.4619397662556434, -0.1913417161825449,
 -0.1913417161825449,  0.4619397662556434, -0.4619397662556434,  0.1913417161825449,

  0.0975451610080641, -0.2777851165098011,  0.4157348061512726, -0.4903926402016152,
  0.4903926402016152, -0.4157348061512726,  0.2777851165098011, -0.0975451610080641
};

__global__ __launch_bounds__(256) void jpeg_fused(
    const float* __restrict__ in, const float* __restrict__ quant,
    float* __restrict__ out)
{
    __shared__ double Dsd[64];
    __shared__ double Ad[6][64];   // blocks 0..3 = Y quads, 4 = Cb, 5 = Cr
    __shared__ double Bd[6][64];
    __shared__ float  Af[6][64];
    __shared__ float  Bf[6][64];

    const int t = threadIdx.x;
    const int tile = blockIdx.x;
    const int b    = tile >> 10;        // 1024 tiles per image
    const int trow = (tile >> 5) & 31;
    const int tcol = tile & 31;

    if (t < 64) Dsd[t] = DMATD[t];

    const int h = t >> 4;               // 0..15 within tile
    const int w = t & 15;
    const size_t ibase = (size_t)b * 786432u
                       + (size_t)(trow * 16 + h) * 512u
                       + (size_t)(tcol * 16 + w);

    const double r  = (double)in[ibase];
    const double g  = (double)in[ibase + 262144];
    const double bl = (double)in[ibase + 524288];

    // RGB -> YCC (+off, clip [0,1], -LEVEL) in f64
    double y  =  0.299       * r + 0.587       * g + 0.114       * bl;
    double cb = -0.168735892 * r - 0.331264108 * g + 0.5         * bl;
    double cr =  0.5         * r - 0.418687589 * g - 0.081312411 * bl;
    y  = fmin(fmax(y,          0.0), 1.0) - LEVELD;
    cb = fmin(fmax(cb + LEVELD,0.0), 1.0) - LEVELD;
    cr = fmin(fmax(cr + LEVELD,0.0), 1.0) - LEVELD;

    // 2x2 chroma average via wave shuffles (quad lanes: ^1, ^16; wave-local)
    double scb = cb + __shfl_xor(cb, 1);
    scb       += __shfl_xor(scb, 16);
    double scr = cr + __shfl_xor(cr, 1);
    scr       += __shfl_xor(scr, 16);

    const int yq = ((h >> 3) << 1) | (w >> 3);   // which Y 8x8 block
    Ad[yq][(h & 7) * 8 + (w & 7)] = y;
    if (((h | w) & 1) == 0) {
        Ad[4][(h >> 1) * 8 + (w >> 1)] = 0.25 * scb;
        Ad[5][(h >> 1) * 8 + (w >> 1)] = 0.25 * scr;
    }
    __syncthreads();

    // matmul-stage mapping: element (ii,jj) of Y block tq; threads <128 also
    // handle chroma block 4+tq.
    const int tq = t >> 6;
    const int ii = (t >> 3) & 7;
    const int jj = t & 7;
    const double qv = rint((double)quant[(ii << 3) | jj] * 255.0) * (1.0 / 255.0);

    // stage 1 (f64): tmp = D @ X
    {
        double s = 0.0;
        #pragma unroll
        for (int k = 0; k < 8; ++k) s += Dsd[ii*8+k] * Ad[tq][k*8+jj];
        Bd[tq][ii*8+jj] = s;
        if (t < 128) {
            double s2 = 0.0;
            #pragma unroll
            for (int k = 0; k < 8; ++k) s2 += Dsd[ii*8+k] * Ad[4+tq][k*8+jj];
            Bd[4+tq][ii*8+jj] = s2;
        }
    }
    __syncthreads();

    // stage 2 (f64): d = tmp @ D^T, quantize-round-dequant; result -> f32 LDS
    {
        double s = 0.0;
        #pragma unroll
        for (int k = 0; k < 8; ++k) s += Bd[tq][ii*8+k] * Dsd[jj*8+k];
        Af[tq][ii*8+jj] = (float)(rint(s / qv) * qv);
        if (t < 128) {
            double s2 = 0.0;
            #pragma unroll
            for (int k = 0; k < 8; ++k) s2 += Bd[4+tq][ii*8+k] * Dsd[jj*8+k];
            Af[4+tq][ii*8+jj] = (float)(rint(s2 / qv) * qv);
        }
    }
    __syncthreads();

    // stage 3 (f32): e = D^T @ dec
    {
        float s = 0.0f;
        #pragma unroll
        for (int k = 0; k < 8; ++k) s += (float)Dsd[k*8+ii] * Af[tq][k*8+jj];
        Bf[tq][ii*8+jj] = s;
        if (t < 128) {
            float s2 = 0.0f;
            #pragma unroll
            for (int k = 0; k < 8; ++k) s2 += (float)Dsd[k*8+ii] * Af[4+tq][k*8+jj];
            Bf[4+tq][ii*8+jj] = s2;
        }
    }
    __syncthreads();

    // stage 4 (f32): out = e @ D
    {
        float s = 0.0f;
        #pragma unroll
        for (int k = 0; k < 8; ++k) s += Bf[tq][ii*8+k] * (float)Dsd[k*8+jj];
        Af[tq][ii*8+jj] = s;
        if (t < 128) {
            float s2 = 0.0f;
            #pragma unroll
            for (int k = 0; k < 8; ++k) s2 += Bf[4+tq][ii*8+k] * (float)Dsd[k*8+jj];
            Af[4+tq][ii*8+jj] = s2;
        }
    }
    __syncthreads();

    // reconstruct (f32): Y + LEVEL; chroma offsets cancel. YCC -> RGB, clamp.
    const float y2  = Af[yq][(h & 7) * 8 + (w & 7)] + LEVELF;
    const float cb2 = Af[4][(h >> 1) * 8 + (w >> 1)];
    const float cr2 = Af[5][(h >> 1) * 8 + (w >> 1)];

    float rr = y2 + 1.402f * cr2;
    float gg = y2 - 0.344136286f * cb2 - 0.714136286f * cr2;
    float bb = y2 + 1.772f * cb2;
    rr = fminf(fmaxf(rr, 0.0f), 1.0f);
    gg = fminf(fmaxf(gg, 0.0f), 1.0f);
    bb = fminf(fmaxf(bb, 0.0f), 1.0f);

    out[ibase]          = rr;
    out[ibase + 262144] = gg;
    out[ibase + 524288] = bb;
}

extern "C" void kernel_launch(void* const* d_in, const int* in_sizes, int n_in,
                              void* d_out, int out_size, void* d_ws, size_t ws_size,
                              hipStream_t stream) {
    const float* in    = (const float*)d_in[0];
    const float* quant = (const float*)d_in[1];  // only quantize[0] (64 floats) used
    float* out = (float*)d_out;

    const int n_tiles = 32 * 32 * 32;  // B * (512/16)^2
    jpeg_fused<<<dim3(n_tiles), dim3(256), 0, stream>>>(in, quant, out);
}

// Round 3
// 69.762 us; speedup vs baseline: 1.1365x; 1.1365x over previous
//
#include <hip/hip_runtime.h>
#include <cmath>

// JPEG layer, fully fused, f32 fast path + rare f64 "rescue" for quantizer
// round() decisions near half-integer boundaries.
// Workgroup = 256 threads, processes 4 16x16 tiles. Wave w owns 8x8 block w
// (waves 0,1 additionally own chroma blocks Cb,Cr). All matmul stages read
// contiguous LDS rows (ds_read_b128, broadcast) with D rows/cols in registers.

#define LEVELD 0.5019607843137255
#define LEVELF 0.5019607843137255f

#define CA  0.35355339059327373f
#define CB0 0.49039264020161522f
#define CB1 0.41573480615127262f
#define CB2 0.27778511650980114f
#define CB3 0.09754516100806413f
#define CC0 0.46193976625564337f
#define CC1 0.19134171618254489f

__device__ __constant__ float DMATF[64] = {  // D, row-major
  CA,  CA,  CA,  CA,   CA,  CA,  CA,  CA,
  CB0, CB1, CB2, CB3, -CB3,-CB2,-CB1,-CB0,
  CC0, CC1,-CC1,-CC0, -CC0,-CC1, CC1, CC0,
  CB1,-CB3,-CB0,-CB2,  CB2, CB0, CB3,-CB1,
  CA, -CA, -CA,  CA,   CA, -CA, -CA,  CA,
  CB2,-CB0, CB3, CB1, -CB1,-CB3, CB0,-CB2,
  CC1,-CC0, CC0,-CC1, -CC1, CC0,-CC0, CC1,
  CB3,-CB2, CB1,-CB0,  CB0,-CB1, CB2,-CB3
};
__device__ __constant__ float DMATTF[64] = { // D^T, row-major (= columns of D)
  CA,  CB0, CC0, CB1,  CA,  CB2, CC1, CB3,
  CA,  CB1, CC1,-CB3, -CA, -CB0,-CC0,-CB2,
  CA,  CB2,-CC1,-CB0, -CA,  CB3, CC0, CB1,
  CA,  CB3,-CC0,-CB2,  CA,  CB1,-CC1,-CB0,
  CA, -CB3,-CC0, CB2,  CA, -CB1,-CC1, CB0,
  CA, -CB2,-CC1, CB0, -CA, -CB3, CC0,-CB1,
  CA, -CB1, CC1, CB3, -CA,  CB0,-CC0, CB2,
  CA, -CB0, CC0,-CB1,  CA, -CB2, CC1,-CB3
};

__device__ __constant__ double DMATD[64] = { // D in f64 (rescue path)
  0.3535533905932738,  0.3535533905932738,  0.3535533905932738,  0.3535533905932738,
  0.3535533905932738,  0.3535533905932738,  0.3535533905932738,  0.3535533905932738,
  0.4903926402016152,  0.4157348061512726,  0.2777851165098011,  0.0975451610080641,
 -0.0975451610080641, -0.2777851165098011, -0.4157348061512726, -0.4903926402016152,
  0.4619397662556434,  0.1913417161825449, -0.1913417161825449, -0.4619397662556434,
 -0.4619397662556434, -0.1913417161825449,  0.1913417161825449,  0.4619397662556434,
  0.4157348061512726, -0.0975451610080641, -0.4903926402016152, -0.2777851165098011,
  0.2777851165098011,  0.4903926402016152,  0.0975451610080641, -0.4157348061512726,
  0.3535533905932738, -0.3535533905932738, -0.3535533905932738,  0.3535533905932738,
  0.3535533905932738, -0.3535533905932738, -0.3535533905932738,  0.3535533905932738,
  0.2777851165098011, -0.4903926402016152,  0.0975451610080641,  0.4157348061512726,
 -0.4157348061512726, -0.0975451610080641,  0.4903926402016152, -0.2777851165098011,
  0.1913417161825449, -0.4619397662556434,  0.4619397662556434, -0.1913417161825449,
 -0.1913417161825449,  0.4619397662556434, -0.4619397662556434,  0.1913417161825449,
  0.0975451610080641, -0.2777851165098011,  0.4157348061512726, -0.4903926402016152,
  0.4903926402016152, -0.4157348061512726,  0.2777851165098011, -0.0975451610080641
};

__device__ __forceinline__ float dot8(const float4 a0, const float4 a1,
                                      const float* __restrict__ row) {
    const float4 b0 = *reinterpret_cast<const float4*>(row);
    const float4 b1 = *reinterpret_cast<const float4*>(row + 4);
    float s = a0.x * b0.x;
    s = fmaf(a0.y, b0.y, s);
    s = fmaf(a0.z, b0.z, s);
    s = fmaf(a0.w, b0.w, s);
    s = fmaf(a1.x, b1.x, s);
    s = fmaf(a1.y, b1.y, s);
    s = fmaf(a1.z, b1.z, s);
    s = fmaf(a1.w, b1.w, s);
    return s;
}

#define RESCUE_BAND 1.5e-4f

__global__ __launch_bounds__(256) void jpeg_fused(
    const float* __restrict__ in, const float* __restrict__ quant,
    float* __restrict__ out)
{
    __shared__ __align__(16) float P[6][64];
    __shared__ __align__(16) float Q[6][64];
    __shared__ double Yd[4][64];    // f64 Y blocks (natural layout), rescue only
    __shared__ double CbS[256];     // f64 per-pixel cb, rescue only
    __shared__ double CrS[256];     // f64 per-pixel cr, rescue only

    const int t   = threadIdx.x;
    const int wid = t >> 6;
    const int r   = (t >> 3) & 7;   // compute-task row
    const int c   = t & 7;          // compute-task col
    const int h   = t >> 4;         // pixel row in tile
    const int w   = t & 15;         // pixel col in tile
    const int yq  = ((h >> 3) << 1) | (w >> 3);
    const int bi  = h & 7, bj = w & 7;
    const int hc  = h >> 1, wc = w >> 1;

    // D rows/cols in registers (loaded once)
    const float4 Rr0 = *reinterpret_cast<const float4*>(&DMATF[r*8]);
    const float4 Rr1 = *reinterpret_cast<const float4*>(&DMATF[r*8+4]);
    const float4 Rc0 = *reinterpret_cast<const float4*>(&DMATF[c*8]);
    const float4 Rc1 = *reinterpret_cast<const float4*>(&DMATF[c*8+4]);
    const float4 Tr0 = *reinterpret_cast<const float4*>(&DMATTF[r*8]);
    const float4 Tr1 = *reinterpret_cast<const float4*>(&DMATTF[r*8+4]);
    const float4 Tc0 = *reinterpret_cast<const float4*>(&DMATTF[c*8]);
    const float4 Tc1 = *reinterpret_cast<const float4*>(&DMATTF[c*8+4]);

    const double qvd = rint((double)quant[r*8 + c] * 255.0) * (1.0/255.0);
    const float  qvf = (float)qvd;
    const float  rqf = (float)(1.0 / qvd);

    for (int it = 0; it < 4; ++it) {
        if (it) __syncthreads();      // protect LDS reuse across tiles
        const int tile = blockIdx.x * 4 + it;
        const int b    = tile >> 10;
        const int trow = (tile >> 5) & 31;
        const int tcol = tile & 31;
        const size_t ibase = (size_t)b * 786432u
                           + (size_t)(trow*16 + h) * 512u
                           + (size_t)(tcol*16 + w);

        // ---- pixel phase: RGB -> YCC (f64), stage into LDS ----
        const double rr = (double)in[ibase];
        const double gg = (double)in[ibase + 262144];
        const double bb = (double)in[ibase + 524288];

        double y  =  0.299*rr       + 0.587*gg       + 0.114*bb;
        double cb = -0.168735892*rr - 0.331264108*gg + 0.5*bb;
        double cr =  0.5*rr         - 0.418687589*gg - 0.081312411*bb;
        y  = fmin(fmax(y,          0.0), 1.0) - LEVELD;
        cb = fmin(fmax(cb + LEVELD,0.0), 1.0) - LEVELD;
        cr = fmin(fmax(cr + LEVELD,0.0), 1.0) - LEVELD;

        P[yq][bj*8 + bi] = (float)y;   // X^T (f32 fast path)
        Yd[yq][bi*8 + bj] = y;         // natural (rescue)
        CbS[t] = cb;
        CrS[t] = cr;

        const float cbf = (float)cb, crf = (float)cr;
        float scb = cbf + __shfl_xor(cbf, 1);
        scb += __shfl_xor(scb, 16);
        float scr = crf + __shfl_xor(crf, 1);
        scr += __shfl_xor(scr, 16);
        if (((h | w) & 1) == 0) {
            P[4][wc*8 + hc] = 0.25f * scb;   // Cb^T
            P[5][wc*8 + hc] = 0.25f * scr;   // Cr^T
        }
        __syncthreads();

        // ---- stage 1: S1 = D @ X.  S1[r][c] = rowD_r . X^T-row-c ----
        {
            const float s = dot8(Rr0, Rr1, &P[wid][c*8]);
            Q[wid][r*8 + c] = s;
            if (wid < 2) {
                const float s2 = dot8(Rr0, Rr1, &P[4+wid][c*8]);
                Q[4+wid][r*8 + c] = s2;
            }
        }
        __builtin_amdgcn_wave_barrier();

        // ---- stage 2: d = S1 @ D^T; quantize-round-dequant; write dec^T ----
        {
            const float s = dot8(Rc0, Rc1, &Q[wid][r*8]);
            const float tt = s * rqf;
            float rt = rintf(tt);
            if (fabsf(tt - rt) > 0.5f - RESCUE_BAND) {   // f64 rescue (rare)
                double acc = 0.0;
                #pragma unroll 1
                for (int k = 0; k < 8; ++k) {
                    double e = 0.0;
                    for (int l = 0; l < 8; ++l)
                        e += Yd[wid][k*8 + l] * DMATD[c*8 + l];
                    acc += DMATD[r*8 + k] * e;
                }
                rt = (float)rint(acc / qvd);
            }
            P[wid][c*8 + r] = rt * qvf;
            if (wid < 2) {
                const float s2 = dot8(Rc0, Rc1, &Q[4+wid][r*8]);
                const float tt2 = s2 * rqf;
                float rt2 = rintf(tt2);
                if (fabsf(tt2 - rt2) > 0.5f - RESCUE_BAND) {
                    const double* S = (wid == 0) ? CbS : CrS;
                    double acc = 0.0;
                    #pragma unroll 1
                    for (int k = 0; k < 8; ++k) {
                        double e = 0.0;
                        for (int l = 0; l < 8; ++l) {
                            const double m = 0.25 * (S[(2*k)*16 + 2*l]   + S[(2*k)*16 + 2*l+1]
                                                   + S[(2*k+1)*16 + 2*l] + S[(2*k+1)*16 + 2*l+1]);
                            e += m * DMATD[c*8 + l];
                        }
                        acc += DMATD[r*8 + k] * e;
                    }
                    rt2 = (float)rint(acc / qvd);
                }
                P[4+wid][c*8 + r] = rt2 * qvf;
            }
        }
        __builtin_amdgcn_wave_barrier();

        // ---- stage 3: S3 = D^T @ dec.  S3[r][c] = colD_r . dec^T-row-c ----
        {
            const float s = dot8(Tr0, Tr1, &P[wid][c*8]);
            Q[wid][r*8 + c] = s;
            if (wid < 2) {
                const float s2 = dot8(Tr0, Tr1, &P[4+wid][c*8]);
                Q[4+wid][r*8 + c] = s2;
            }
        }
        __builtin_amdgcn_wave_barrier();

        // ---- stage 4: out = S3 @ D.  S4[r][c] = colD_c . S3-row-r ----
        {
            const float s = dot8(Tc0, Tc1, &Q[wid][r*8]);
            P[wid][r*8 + c] = s;                 // natural layout
            if (wid < 2) {
                const float s2 = dot8(Tc0, Tc1, &Q[4+wid][r*8]);
                P[4+wid][r*8 + c] = s2;
            }
        }
        __syncthreads();

        // ---- gather: upsample chroma, YCC -> RGB, clamp, store ----
        const float y2  = P[yq][bi*8 + bj] + LEVELF;
        const float cb2 = P[4][hc*8 + wc];
        const float cr2 = P[5][hc*8 + wc];

        float ro = fmaf(1.402f, cr2, y2);
        float go = y2 - 0.344136286f*cb2 - 0.714136286f*cr2;
        float bo = fmaf(1.772f, cb2, y2);
        ro = fminf(fmaxf(ro, 0.0f), 1.0f);
        go = fminf(fmaxf(go, 0.0f), 1.0f);
        bo = fminf(fmaxf(bo, 0.0f), 1.0f);

        out[ibase]          = ro;
        out[ibase + 262144] = go;
        out[ibase + 524288] = bo;
    }
}

extern "C" void kernel_launch(void* const* d_in, const int* in_sizes, int n_in,
                              void* d_out, int out_size, void* d_ws, size_t ws_size,
                              hipStream_t stream) {
    const float* in    = (const float*)d_in[0];
    const float* quant = (const float*)d_in[1];  // only quantize[0] (64 floats) used
    float* out = (float*)d_out;

    const int n_groups = 32 * 32 * 32 / 4;   // 4 tiles per workgroup
    jpeg_fused<<<dim3(n_groups), dim3(256), 0, stream>>>(in, quant, out);
}